// Round 1
// 263.931 us; speedup vs baseline: 1.0107x; 1.0107x over previous
//
#include <hip/hip_runtime.h>
#include <hip/hip_bf16.h>
#include <cstdint>

// B=2, HW=64 -> 128 rows of S=256; M = 32768. D=512, HEADS=8, DK=64,
// 3*H*DK=1536, KSIZE=7. Inputs/outputs fp32; internal compute bf16 MFMA.

typedef __bf16 bf16x8 __attribute__((ext_vector_type(8)));
typedef float f32x4 __attribute__((ext_vector_type(4)));

__device__ __forceinline__ uint16_t f2bf(float f) {
    uint32_t u = __builtin_bit_cast(uint32_t, f);
    return (uint16_t)((u + 0x7fffu + ((u >> 16) & 1u)) >> 16);
}
__device__ __forceinline__ float bflo(uint32_t u) { return __builtin_bit_cast(float, u << 16); }
__device__ __forceinline__ float bfhi(uint32_t u) { return __builtin_bit_cast(float, u & 0xffff0000u); }

__device__ __forceinline__ void unpack8(uint4 v, float* f) {
    f[0] = bflo(v.x); f[1] = bfhi(v.x);
    f[2] = bflo(v.y); f[3] = bfhi(v.y);
    f[4] = bflo(v.z); f[5] = bfhi(v.z);
    f[6] = bflo(v.w); f[7] = bfhi(v.w);
}
__device__ __forceinline__ uint32_t pack2(float a, float b) {
    return (uint32_t)f2bf(a) | ((uint32_t)f2bf(b) << 16);
}

#define GLOAD_LDS16(gp, lp)                                                        \
    __builtin_amdgcn_global_load_lds((const __attribute__((address_space(1))) void*)(gp), \
                                     (__attribute__((address_space(3))) void*)(lp), 16, 0, 0)

// ---------------------------------------------------------------------------
// fp32 -> bf16 bulk convert, 8 elems/thread
// ---------------------------------------------------------------------------
__global__ void cvt_f32_bf16(const float* __restrict__ in, uint16_t* __restrict__ out, int n8) {
    int i = blockIdx.x * 256 + threadIdx.x;
    if (i >= n8) return;
    const float4* p = (const float4*)in + (size_t)i * 2;
    float4 a = p[0], b = p[1];
    uint4 o;
    o.x = pack2(a.x, a.y);
    o.y = pack2(a.z, a.w);
    o.z = pack2(b.x, b.y);
    o.w = pack2(b.z, b.w);
    *((uint4*)out + i) = o;
}

// ---------------------------------------------------------------------------
// transpose + convert: out[c*R + r] = bf16(in[r*C + c])
// ---------------------------------------------------------------------------
__global__ void transpose_cvt(const float* __restrict__ in, uint16_t* __restrict__ out,
                              int R, int C) {
    int idx = blockIdx.x * 256 + threadIdx.x;
    if (idx >= R * C) return;
    int r = idx / C;
    int c = idx - r * C;
    out[(size_t)c * R + r] = f2bf(in[idx]);
}

// ---------------------------------------------------------------------------
// 256x256-tile 8-phase bf16 GEMM (T2+T3+T4+T5).
// C[M,N] = A[M,K] @ B[K,N], B given transposed (BT[N,K]).
// 512 threads = 8 waves (2 M-waves x 4 N-waves), per-wave 128x64 output
// (acc[8][4] of 16x16 frags). BK=64, double-buffered LDS = 128 KiB
// (A: 2 x 256x64, B: 2 x 256x64 bf16), 1 block/CU.
//
// LDS swizzle: 16B k-chunk index cc stored at cc ^ (row&7); global source is
// pre-swizzled so global_load_lds dest stays linear; ds_read applies the same
// XOR (both-sides rule). Makes stride-128B b128 reads bank-uniform.
//
// Schedule per K-tile t (buffer b = t&1), 4 phases, 16 MFMA each:
//   p0: ds_read all 8 B-frags + A mf{0,1}; stage A-h0(t+1) -> bufA[b^1]
//   p1: ds_read A mf{2,3};                 stage A-h1(t+1) -> bufA[b^1]
//   p2: ds_read A mf{4,5};                 stage B-h0(t+2) -> bufB[b]
//   p3: ds_read A mf{6,7};                 stage B-h1(t+2) -> bufB[b]
//   end: s_waitcnt vmcnt(4) (leaves only B(t+2) in flight) + barrier.
// Race-safety: bufA[b^1] was last read in tile t-1 (drained before t);
// bufB[b]'s reads all happen in p0 and every wave's p0 lgkmcnt(0) has
// executed before any wave reaches p2 (two barriers in between). The
// vmcnt(4)+barrier at tile end guarantees tile t+1 fully resident.
// Assumes K % 64 == 0 and K/64 >= 3 (here K=512 -> NT=8).
// ---------------------------------------------------------------------------
template <bool F32OUT>
__global__ __launch_bounds__(512, 2)
void gemm256(const uint16_t* __restrict__ A, const uint16_t* __restrict__ BT,
             void* __restrict__ Cout, int M, int N, int K) {
    __shared__ __align__(16) uint16_t lds[65536];  // [0,32768): A bufs, [32768,65536): B bufs

    const int tid  = threadIdx.x;
    const int lane = tid & 63;
    const int wv   = tid >> 6;
    const int r    = lane & 15;
    const int quad = lane >> 4;
    const int wr   = wv >> 2;   // 0..1  (M wave)
    const int wc   = wv & 3;    // 0..3  (N wave)
    const long bm0 = (long)blockIdx.x * 256;
    const long bn0 = (long)blockIdx.y * 256;
    const int NT   = K >> 6;

    // ---- staging constants: thread handles 16B chunks c0, c1 of each half ----
    const int c0 = tid, c1 = tid + 512;
    const int row0 = c0 >> 3, row1 = c1 >> 3;          // row within 128-row half
    const int sw0 = ((c0 & 7) ^ (row0 & 7)) * 8;       // pre-swizzled k-chunk (elems)
    const int sw1 = ((c1 & 7) ^ (row1 & 7)) * 8;
    const uint16_t* pA0 = A  + (bm0 + row0) * (long)K + sw0;
    const uint16_t* pA1 = A  + (bm0 + row1) * (long)K + sw1;
    const uint16_t* pB0 = BT + (bn0 + row0) * (long)K + sw0;
    const uint16_t* pB1 = BT + (bn0 + row1) * (long)K + sw1;
    const long hstep = 128 * (long)K;

#define STAGE_A(b_, h_, t_) do {                                                        \
        GLOAD_LDS16(pA0 + (h_) * hstep + (t_) * 64,                                     \
                    &lds[(b_) * 16384 + (h_) * 8192 + c0 * 8]);                         \
        GLOAD_LDS16(pA1 + (h_) * hstep + (t_) * 64,                                     \
                    &lds[(b_) * 16384 + (h_) * 8192 + c1 * 8]);                         \
    } while (0)
#define STAGE_B(b_, h_, t_) do {                                                        \
        GLOAD_LDS16(pB0 + (h_) * hstep + (t_) * 64,                                     \
                    &lds[32768 + (b_) * 16384 + (h_) * 8192 + c0 * 8]);                 \
        GLOAD_LDS16(pB1 + (h_) * hstep + (t_) * 64,                                     \
                    &lds[32768 + (b_) * 16384 + (h_) * 8192 + c1 * 8]);                 \
    } while (0)

    // ---- compute-side constants ----
    const int swk0 = ((0 + quad) ^ (r & 7)) * 8;   // kk=0 swizzled chunk (elems)
    const int swk1 = ((4 + quad) ^ (r & 7)) * 8;   // kk=1
    const int arow = (wr * 128 + r) * 64;          // elem offset of A row base
    const int brow = (wc * 64 + r) * 64;           // elem offset of B row base

#define DS_A(mf_, kk_) (*(const bf16x8*)&lds[aoff + arow + (mf_) * 1024 + ((kk_) ? swk1 : swk0)])
#define DS_B(nf_, kk_) (*(const bf16x8*)&lds[boff + brow + (nf_) * 1024 + ((kk_) ? swk1 : swk0)])

    f32x4 acc[8][4];
#pragma unroll
    for (int mf = 0; mf < 8; ++mf)
#pragma unroll
        for (int nf = 0; nf < 4; ++nf) acc[mf][nf] = (f32x4){0.f, 0.f, 0.f, 0.f};

    // ---- prologue: tile0 (A+B) + tile1 B; leave only tile1-B in flight ----
    STAGE_A(0, 0, 0); STAGE_A(0, 1, 0);
    STAGE_B(0, 0, 0); STAGE_B(0, 1, 0);
    STAGE_B(1, 0, 1); STAGE_B(1, 1, 1);
    asm volatile("s_waitcnt vmcnt(4)" ::: "memory");
    __builtin_amdgcn_s_barrier();

#define MFMA_PHASE(mbase_)                                                              \
    __builtin_amdgcn_s_barrier();                                                       \
    asm volatile("s_waitcnt lgkmcnt(0)");                                               \
    __builtin_amdgcn_s_setprio(1);                                                      \
    _Pragma("unroll")                                                                   \
    for (int kk = 0; kk < 2; ++kk)                                                      \
        _Pragma("unroll")                                                               \
        for (int mi = 0; mi < 2; ++mi)                                                  \
            _Pragma("unroll")                                                           \
            for (int nf = 0; nf < 4; ++nf)                                              \
                acc[(mbase_) + mi][nf] = __builtin_amdgcn_mfma_f32_16x16x32_bf16(       \
                    af[mi][kk], bfr[nf][kk], acc[(mbase_) + mi][nf], 0, 0, 0);          \
    __builtin_amdgcn_s_setprio(0);

    for (int t = 0; t < NT; ++t) {
        const int b    = t & 1;
        const int aoff = b * 16384;
        const int boff = 32768 + b * 16384;

        bf16x8 bfr[4][2];
        bf16x8 af[2][2];

        // ===== phase 0 =====
#pragma unroll
        for (int nf = 0; nf < 4; ++nf) { bfr[nf][0] = DS_B(nf, 0); bfr[nf][1] = DS_B(nf, 1); }
        af[0][0] = DS_A(0, 0); af[0][1] = DS_A(0, 1);
        af[1][0] = DS_A(1, 0); af[1][1] = DS_A(1, 1);
        if (t + 1 < NT) STAGE_A(b ^ 1, 0, t + 1);
        MFMA_PHASE(0)
        __builtin_amdgcn_s_barrier();

        // ===== phase 1 =====
        af[0][0] = DS_A(2, 0); af[0][1] = DS_A(2, 1);
        af[1][0] = DS_A(3, 0); af[1][1] = DS_A(3, 1);
        if (t + 1 < NT) STAGE_A(b ^ 1, 1, t + 1);
        MFMA_PHASE(2)
        __builtin_amdgcn_s_barrier();

        // ===== phase 2 =====
        af[0][0] = DS_A(4, 0); af[0][1] = DS_A(4, 1);
        af[1][0] = DS_A(5, 0); af[1][1] = DS_A(5, 1);
        if (t + 2 < NT) STAGE_B(b, 0, t + 2);
        MFMA_PHASE(4)
        __builtin_amdgcn_s_barrier();

        // ===== phase 3 =====
        af[0][0] = DS_A(6, 0); af[0][1] = DS_A(6, 1);
        af[1][0] = DS_A(7, 0); af[1][1] = DS_A(7, 1);
        if (t + 2 < NT) STAGE_B(b, 1, t + 2);
        MFMA_PHASE(6)
        if (t + 1 < NT) {
            if (t + 2 < NT) asm volatile("s_waitcnt vmcnt(4)" ::: "memory");
            else            asm volatile("s_waitcnt vmcnt(0)" ::: "memory");
            __builtin_amdgcn_s_barrier();
        }
    }

    // ---- epilogue: D[row = quad*4 + i][col = r] per 16x16 frag ----
#pragma unroll
    for (int mf = 0; mf < 8; ++mf) {
#pragma unroll
        for (int i = 0; i < 4; ++i) {
            long m = bm0 + wr * 128 + mf * 16 + quad * 4 + i;
            if (F32OUT) {
                float* crow = (float*)Cout + m * (long)N + bn0 + wc * 64 + r;
#pragma unroll
                for (int nf = 0; nf < 4; ++nf) crow[nf * 16] = acc[mf][nf][i];
            } else {
                uint16_t* crow = (uint16_t*)Cout + m * (long)N + bn0 + wc * 64 + r;
#pragma unroll
                for (int nf = 0; nf < 4; ++nf) crow[nf * 16] = f2bf(acc[mf][nf][i]);
            }
        }
    }
#undef STAGE_A
#undef STAGE_B
#undef DS_A
#undef DS_B
#undef MFMA_PHASE
}

// ---------------------------------------------------------------------------
// Local window attention, LDS-staged K/V.
// Block = (bn, head), 256 threads, thread = s.
// LDS: K tile + V tile = 2 * 256 rows * 64 elems * 2B = 64 KB (2 blocks/CU).
// 16-B chunk column is XOR-swizzled by (sp&7) -> conflict-free for the
// stride-128B compute-phase reads without padding bytes.
// Q is per-thread (read once from global, full cache-line use) in registers.
// Padded window entries (sp out of range): score = bias only, v contributes 0.
// ---------------------------------------------------------------------------
__global__ __launch_bounds__(256, 2)
void local_attn(const uint16_t* __restrict__ qkv, const float* __restrict__ pb,
                uint16_t* __restrict__ attn) {
    __shared__ uint4 smem[4096];  // [0,2048): K chunks, [2048,4096): V chunks

    const int h  = blockIdx.x & 7;
    const int bn = blockIdx.x >> 3;
    const int s  = threadIdx.x;
    const size_t base = (size_t)bn * 256 * 1536;

    // ---- stage K,V: 4096 16-B chunks, 16 per thread, coalesced ----
#pragma unroll
    for (int it = 0; it < 16; ++it) {
        int i   = threadIdx.x + it * 256;
        int a   = i >> 11;        // 0=K, 1=V
        int idx = i & 2047;
        int sp  = idx >> 3;
        int c8  = idx & 7;
        const uint16_t* src = qkv + base + (size_t)sp * 1536 + 512 + a * 512 + h * 64 + c8 * 8;
        smem[a * 2048 + sp * 8 + (c8 ^ (sp & 7))] = *(const uint4*)src;
    }

    // ---- load own Q row into registers (8 x 16B = 128 B) ----
    const uint16_t* qrow = qkv + base + (size_t)s * 1536 + h * 64;
    uint4 qc[8];
#pragma unroll
    for (int c = 0; c < 8; ++c) qc[c] = *(const uint4*)(qrow + c * 8);

    __syncthreads();

    // ---- scores ----
    float sc[7];
#pragma unroll
    for (int w = 0; w < 7; ++w) sc[w] = 0.f;

#pragma unroll
    for (int c = 0; c < 8; ++c) {
        float qf[8];
        unpack8(qc[c], qf);
#pragma unroll
        for (int w = 0; w < 7; ++w) {
            int sp = s + w - 3;
            if ((unsigned)sp < 256u) {
                uint4 kc = smem[sp * 8 + (c ^ (sp & 7))];
                float kf[8];
                unpack8(kc, kf);
#pragma unroll
                for (int j = 0; j < 8; ++j) sc[w] += qf[j] * kf[j];
            }
        }
    }

    const float* pbr = pb + ((size_t)h * 256 + s) * 7;
    float mx = -1e30f;
#pragma unroll
    for (int w = 0; w < 7; ++w) {
        sc[w] = sc[w] * 0.125f + pbr[w];
        mx = fmaxf(mx, sc[w]);
    }
    float p[7], sum = 0.f;
#pragma unroll
    for (int w = 0; w < 7; ++w) {
        p[w] = __expf(sc[w] - mx);
        sum += p[w];
    }
    const float inv = 1.f / sum;
#pragma unroll
    for (int w = 0; w < 7; ++w) p[w] *= inv;

    // ---- output: accumulate all 64 elems in regs, then one contiguous 128-B store ----
    uint4 ov[8];
#pragma unroll
    for (int c = 0; c < 8; ++c) {
        float o[8] = {0.f, 0.f, 0.f, 0.f, 0.f, 0.f, 0.f, 0.f};
#pragma unroll
        for (int w = 0; w < 7; ++w) {
            int sp = s + w - 3;
            if ((unsigned)sp < 256u) {
                uint4 vc = smem[2048 + sp * 8 + (c ^ (sp & 7))];
                float vf[8];
                unpack8(vc, vf);
#pragma unroll
                for (int j = 0; j < 8; ++j) o[j] += p[w] * vf[j];
            }
        }
        ov[c].x = pack2(o[0], o[1]);
        ov[c].y = pack2(o[2], o[3]);
        ov[c].z = pack2(o[4], o[5]);
        ov[c].w = pack2(o[6], o[7]);
    }

    uint16_t* orow = attn + ((size_t)(bn * 256 + s)) * 512 + h * 64;
#pragma unroll
    for (int c = 0; c < 8; ++c) *(uint4*)(orow + c * 8) = ov[c];
}

// ---------------------------------------------------------------------------
extern "C" void kernel_launch(void* const* d_in, const int* in_sizes, int n_in,
                              void* d_out, int out_size, void* d_ws, size_t ws_size,
                              hipStream_t stream) {
    const float* X    = (const float*)d_in[0];  // 32768 x 512 fp32
    const float* pb   = (const float*)d_in[1];  // 8 x 256 x 7 fp32
    const float* Wqkv = (const float*)d_in[2];  // 512 x 1536 fp32
    const float* Wout = (const float*)d_in[3];  // 512 x 512 fp32
    float* out = (float*)d_out;                 // 32768 x 512 fp32

    char* ws = (char*)d_ws;
    uint16_t* WqkvT = (uint16_t*)(ws);                  // 1536x512 bf16 = 1.5 MB
    uint16_t* WoutT = (uint16_t*)(ws + 1572864);        // 512x512  bf16 = 0.5 MB
    uint16_t* qkvb  = (uint16_t*)(ws + 2097152);        // 32768x1536 bf16 = 96 MB
    uint16_t* Xb    = (uint16_t*)(ws + 102760448);      // 32768x512 bf16 = 32 MB
    uint16_t* attnb = Xb;  // alias: Xb dead after GEMM1 (stream-ordered)

    cvt_f32_bf16<<<(32768 * 512 / 8 + 255) / 256, 256, 0, stream>>>(X, Xb, 32768 * 512 / 8);
    transpose_cvt<<<(512 * 1536 + 255) / 256, 256, 0, stream>>>(Wqkv, WqkvT, 512, 1536);
    transpose_cvt<<<(512 * 512 + 255) / 256, 256, 0, stream>>>(Wout, WoutT, 512, 512);

    gemm256<false><<<dim3(128, 6), 512, 0, stream>>>(Xb, WqkvT, qkvb, 32768, 1536, 512);
    local_attn<<<1024, 256, 0, stream>>>(qkvb, pb, attnb);
    gemm256<true><<<dim3(128, 2), 512, 0, stream>>>(attnb, WoutT, out, 32768, 512, 512);
}

// Round 2
// 258.188 us; speedup vs baseline: 1.0332x; 1.0222x over previous
//
#include <hip/hip_runtime.h>
#include <hip/hip_bf16.h>
#include <cstdint>

// B=2, HW=64 -> 128 rows of S=256; M = 32768. D=512, HEADS=8, DK=64,
// 3*H*DK=1536, KSIZE=7. Inputs/outputs fp32; internal compute bf16 MFMA.

typedef __bf16 bf16x8 __attribute__((ext_vector_type(8)));
typedef float f32x4 __attribute__((ext_vector_type(4)));

__device__ __forceinline__ uint16_t f2bf(float f) {
    uint32_t u = __builtin_bit_cast(uint32_t, f);
    return (uint16_t)((u + 0x7fffu + ((u >> 16) & 1u)) >> 16);
}
__device__ __forceinline__ float bflo(uint32_t u) { return __builtin_bit_cast(float, u << 16); }
__device__ __forceinline__ float bfhi(uint32_t u) { return __builtin_bit_cast(float, u & 0xffff0000u); }

__device__ __forceinline__ void unpack8(uint4 v, float* f) {
    f[0] = bflo(v.x); f[1] = bfhi(v.x);
    f[2] = bflo(v.y); f[3] = bfhi(v.y);
    f[4] = bflo(v.z); f[5] = bfhi(v.z);
    f[6] = bflo(v.w); f[7] = bfhi(v.w);
}
__device__ __forceinline__ uint32_t pack2(float a, float b) {
    return (uint32_t)f2bf(a) | ((uint32_t)f2bf(b) << 16);
}

#define GLOAD_LDS16(gp, lp)                                                        \
    __builtin_amdgcn_global_load_lds((const __attribute__((address_space(1))) void*)(gp), \
                                     (__attribute__((address_space(3))) void*)(lp), 16, 0, 0)

// Inline-asm LDS read: invisible to the compiler's waitcnt/alias tracking, so
// no automatic vmcnt(0) drain is inserted against in-flight global_load_lds.
// Caller owns lgkmcnt discipline (s_waitcnt lgkmcnt(0) + sched_barrier(0)
// before any MFMA consuming the result -- rule #18).
__device__ __forceinline__ bf16x8 ds_read16(const uint16_t* p) {
    bf16x8 r;
    asm volatile("ds_read_b128 %0, %1"
                 : "=v"(r)
                 : "v"((const __attribute__((address_space(3))) void*)p));
    return r;
}

// ---------------------------------------------------------------------------
// fp32 -> bf16 bulk convert, 8 elems/thread
// ---------------------------------------------------------------------------
__global__ void cvt_f32_bf16(const float* __restrict__ in, uint16_t* __restrict__ out, int n8) {
    int i = blockIdx.x * 256 + threadIdx.x;
    if (i >= n8) return;
    const float4* p = (const float4*)in + (size_t)i * 2;
    float4 a = p[0], b = p[1];
    uint4 o;
    o.x = pack2(a.x, a.y);
    o.y = pack2(a.z, a.w);
    o.z = pack2(b.x, b.y);
    o.w = pack2(b.z, b.w);
    *((uint4*)out + i) = o;
}

// ---------------------------------------------------------------------------
// transpose + convert: out[c*R + r] = bf16(in[r*C + c])
// ---------------------------------------------------------------------------
__global__ void transpose_cvt(const float* __restrict__ in, uint16_t* __restrict__ out,
                              int R, int C) {
    int idx = blockIdx.x * 256 + threadIdx.x;
    if (idx >= R * C) return;
    int r = idx / C;
    int c = idx - r * C;
    out[(size_t)c * R + r] = f2bf(in[idx]);
}

// ---------------------------------------------------------------------------
// 256x256-tile 8-phase bf16 GEMM (T2+T3+T4+T5), inline-asm ds_read variant.
// C[M,N] = A[M,K] @ B[K,N], B given transposed (BT[N,K]).
// 512 threads = 8 waves (2 M-waves x 4 N-waves), per-wave 128x64 output
// (acc[8][4] of 16x16 frags). BK=64, double-buffered LDS = 128 KiB.
//
// LDS swizzle: 16B k-chunk index cc stored at cc ^ (row&7); global source is
// pre-swizzled so global_load_lds dest stays linear; ds_read applies the same
// XOR (both-sides rule).
//
// Schedule per K-tile t (buffer b = t&1), 4 phases, 16 MFMA each:
//   p0: ds_read all 8 B-frags + A mf{0,1}; stage A-h0(t+1) -> bufA[b^1]
//   p1: ds_read A mf{2,3};                 stage A-h1(t+1) -> bufA[b^1]
//   p2: ds_read A mf{4,5};                 stage B-h0(t+2) -> bufB[b]
//   p3: ds_read A mf{6,7};                 stage B-h1(t+2) -> bufB[b]
//   end: s_waitcnt vmcnt(4) (leaves only B(t+2) in flight) + barrier.
// Race-safety: bufA[b^1] last read in tile t-1 (drained before t); bufB[b]'s
// reads all happen in p0 and every wave's p0 lgkmcnt(0) precedes the two
// barriers before p2's stage issue. vmcnt(4)+barrier at tile end guarantees
// tile t+1 fully resident. Assumes K % 64 == 0, K/64 >= 3 (K=512 -> NT=8).
// ---------------------------------------------------------------------------
template <bool F32OUT>
__global__ __launch_bounds__(512, 2)
void gemm256(const uint16_t* __restrict__ A, const uint16_t* __restrict__ BT,
             void* __restrict__ Cout, int M, int N, int K) {
    __shared__ __align__(16) uint16_t lds[65536];  // [0,32768): A bufs, [32768,65536): B bufs

    const int tid  = threadIdx.x;
    const int lane = tid & 63;
    const int wv   = tid >> 6;
    const int r    = lane & 15;
    const int quad = lane >> 4;
    const int wr   = wv >> 2;   // 0..1  (M wave)
    const int wc   = wv & 3;    // 0..3  (N wave)
    const long bm0 = (long)blockIdx.x * 256;
    const long bn0 = (long)blockIdx.y * 256;
    const int NT   = K >> 6;

    // ---- staging constants: thread handles 16B chunks c0, c1 of each half ----
    const int c0 = tid, c1 = tid + 512;
    const int row0 = c0 >> 3, row1 = c1 >> 3;          // row within 128-row half
    const int sw0 = ((c0 & 7) ^ (row0 & 7)) * 8;       // pre-swizzled k-chunk (elems)
    const int sw1 = ((c1 & 7) ^ (row1 & 7)) * 8;
    const uint16_t* pA0 = A  + (bm0 + row0) * (long)K + sw0;
    const uint16_t* pA1 = A  + (bm0 + row1) * (long)K + sw1;
    const uint16_t* pB0 = BT + (bn0 + row0) * (long)K + sw0;
    const uint16_t* pB1 = BT + (bn0 + row1) * (long)K + sw1;
    const long hstep = 128 * (long)K;

#define STAGE_A(b_, h_, t_) do {                                                        \
        GLOAD_LDS16(pA0 + (h_) * hstep + (t_) * 64,                                     \
                    &lds[(b_) * 16384 + (h_) * 8192 + c0 * 8]);                         \
        GLOAD_LDS16(pA1 + (h_) * hstep + (t_) * 64,                                     \
                    &lds[(b_) * 16384 + (h_) * 8192 + c1 * 8]);                         \
    } while (0)
#define STAGE_B(b_, h_, t_) do {                                                        \
        GLOAD_LDS16(pB0 + (h_) * hstep + (t_) * 64,                                     \
                    &lds[32768 + (b_) * 16384 + (h_) * 8192 + c0 * 8]);                 \
        GLOAD_LDS16(pB1 + (h_) * hstep + (t_) * 64,                                     \
                    &lds[32768 + (b_) * 16384 + (h_) * 8192 + c1 * 8]);                 \
    } while (0)

    // ---- compute-side constants ----
    const int swk0 = ((0 + quad) ^ (r & 7)) * 8;   // kk=0 swizzled chunk (elems)
    const int swk1 = ((4 + quad) ^ (r & 7)) * 8;   // kk=1
    const int arow = (wr * 128 + r) * 64;          // elem offset of A row base
    const int brow = (wc * 64 + r) * 64;           // elem offset of B row base

#define DS_A(mf_, kk_) ds_read16(&lds[aoff + arow + (mf_) * 1024 + ((kk_) ? swk1 : swk0)])
#define DS_B(nf_, kk_) ds_read16(&lds[boff + brow + (nf_) * 1024 + ((kk_) ? swk1 : swk0)])

    f32x4 acc[8][4];
#pragma unroll
    for (int mf = 0; mf < 8; ++mf)
#pragma unroll
        for (int nf = 0; nf < 4; ++nf) acc[mf][nf] = (f32x4){0.f, 0.f, 0.f, 0.f};

    // ---- prologue: tile0 (A+B) + tile1 B; leave only tile1-B in flight ----
    STAGE_A(0, 0, 0); STAGE_A(0, 1, 0);
    STAGE_B(0, 0, 0); STAGE_B(0, 1, 0);
    STAGE_B(1, 0, 1); STAGE_B(1, 1, 1);
    asm volatile("s_waitcnt vmcnt(4)" ::: "memory");
    __builtin_amdgcn_s_barrier();

    // barrier -> wait own ds_reads -> fence (rule #18: stop MFMA hoisting
    // above the wait) -> prioritized MFMA cluster.
#define MFMA_PHASE(mbase_)                                                              \
    __builtin_amdgcn_s_barrier();                                                       \
    asm volatile("s_waitcnt lgkmcnt(0)" ::: "memory");                                  \
    __builtin_amdgcn_sched_barrier(0);                                                  \
    __builtin_amdgcn_s_setprio(1);                                                      \
    _Pragma("unroll")                                                                   \
    for (int kk = 0; kk < 2; ++kk)                                                      \
        _Pragma("unroll")                                                               \
        for (int mi = 0; mi < 2; ++mi)                                                  \
            _Pragma("unroll")                                                           \
            for (int nf = 0; nf < 4; ++nf)                                              \
                acc[(mbase_) + mi][nf] = __builtin_amdgcn_mfma_f32_16x16x32_bf16(       \
                    af[mi][kk], bfr[nf][kk], acc[(mbase_) + mi][nf], 0, 0, 0);          \
    __builtin_amdgcn_s_setprio(0);

    for (int t = 0; t < NT; ++t) {
        const int b    = t & 1;
        const int aoff = b * 16384;
        const int boff = 32768 + b * 16384;

        bf16x8 bfr[4][2];
        bf16x8 af[2][2];

        // ===== phase 0 =====
#pragma unroll
        for (int nf = 0; nf < 4; ++nf) { bfr[nf][0] = DS_B(nf, 0); bfr[nf][1] = DS_B(nf, 1); }
        af[0][0] = DS_A(0, 0); af[0][1] = DS_A(0, 1);
        af[1][0] = DS_A(1, 0); af[1][1] = DS_A(1, 1);
        if (t + 1 < NT) STAGE_A(b ^ 1, 0, t + 1);
        MFMA_PHASE(0)
        __builtin_amdgcn_s_barrier();

        // ===== phase 1 =====
        af[0][0] = DS_A(2, 0); af[0][1] = DS_A(2, 1);
        af[1][0] = DS_A(3, 0); af[1][1] = DS_A(3, 1);
        if (t + 1 < NT) STAGE_A(b ^ 1, 1, t + 1);
        MFMA_PHASE(2)
        __builtin_amdgcn_s_barrier();

        // ===== phase 2 =====
        af[0][0] = DS_A(4, 0); af[0][1] = DS_A(4, 1);
        af[1][0] = DS_A(5, 0); af[1][1] = DS_A(5, 1);
        if (t + 2 < NT) STAGE_B(b, 0, t + 2);
        MFMA_PHASE(4)
        __builtin_amdgcn_s_barrier();

        // ===== phase 3 =====
        af[0][0] = DS_A(6, 0); af[0][1] = DS_A(6, 1);
        af[1][0] = DS_A(7, 0); af[1][1] = DS_A(7, 1);
        if (t + 2 < NT) STAGE_B(b, 1, t + 2);
        MFMA_PHASE(6)
        if (t + 1 < NT) {
            if (t + 2 < NT) asm volatile("s_waitcnt vmcnt(4)" ::: "memory");
            else            asm volatile("s_waitcnt vmcnt(0)" ::: "memory");
            __builtin_amdgcn_s_barrier();
        }
    }

    // ---- epilogue: D[row = quad*4 + i][col = r] per 16x16 frag ----
#pragma unroll
    for (int mf = 0; mf < 8; ++mf) {
#pragma unroll
        for (int i = 0; i < 4; ++i) {
            long m = bm0 + wr * 128 + mf * 16 + quad * 4 + i;
            if (F32OUT) {
                float* crow = (float*)Cout + m * (long)N + bn0 + wc * 64 + r;
#pragma unroll
                for (int nf = 0; nf < 4; ++nf) crow[nf * 16] = acc[mf][nf][i];
            } else {
                uint16_t* crow = (uint16_t*)Cout + m * (long)N + bn0 + wc * 64 + r;
#pragma unroll
                for (int nf = 0; nf < 4; ++nf) crow[nf * 16] = f2bf(acc[mf][nf][i]);
            }
        }
    }
#undef STAGE_A
#undef STAGE_B
#undef DS_A
#undef DS_B
#undef MFMA_PHASE
}

// ---------------------------------------------------------------------------
// Local window attention, LDS-staged K/V.
// Block = (bn, head), 256 threads, thread = s.
// LDS: K tile + V tile = 2 * 256 rows * 64 elems * 2B = 64 KB (2 blocks/CU).
// 16-B chunk column is XOR-swizzled by (sp&7) -> conflict-free for the
// stride-128B compute-phase reads without padding bytes.
// Q is per-thread (read once from global, full cache-line use) in registers.
// Padded window entries (sp out of range): score = bias only, v contributes 0.
// ---------------------------------------------------------------------------
__global__ __launch_bounds__(256, 2)
void local_attn(const uint16_t* __restrict__ qkv, const float* __restrict__ pb,
                uint16_t* __restrict__ attn) {
    __shared__ uint4 smem[4096];  // [0,2048): K chunks, [2048,4096): V chunks

    const int h  = blockIdx.x & 7;
    const int bn = blockIdx.x >> 3;
    const int s  = threadIdx.x;
    const size_t base = (size_t)bn * 256 * 1536;

    // ---- stage K,V: 4096 16-B chunks, 16 per thread, coalesced ----
#pragma unroll
    for (int it = 0; it < 16; ++it) {
        int i   = threadIdx.x + it * 256;
        int a   = i >> 11;        // 0=K, 1=V
        int idx = i & 2047;
        int sp  = idx >> 3;
        int c8  = idx & 7;
        const uint16_t* src = qkv + base + (size_t)sp * 1536 + 512 + a * 512 + h * 64 + c8 * 8;
        smem[a * 2048 + sp * 8 + (c8 ^ (sp & 7))] = *(const uint4*)src;
    }

    // ---- load own Q row into registers (8 x 16B = 128 B) ----
    const uint16_t* qrow = qkv + base + (size_t)s * 1536 + h * 64;
    uint4 qc[8];
#pragma unroll
    for (int c = 0; c < 8; ++c) qc[c] = *(const uint4*)(qrow + c * 8);

    __syncthreads();

    // ---- scores ----
    float sc[7];
#pragma unroll
    for (int w = 0; w < 7; ++w) sc[w] = 0.f;

#pragma unroll
    for (int c = 0; c < 8; ++c) {
        float qf[8];
        unpack8(qc[c], qf);
#pragma unroll
        for (int w = 0; w < 7; ++w) {
            int sp = s + w - 3;
            if ((unsigned)sp < 256u) {
                uint4 kc = smem[sp * 8 + (c ^ (sp & 7))];
                float kf[8];
                unpack8(kc, kf);
#pragma unroll
                for (int j = 0; j < 8; ++j) sc[w] += qf[j] * kf[j];
            }
        }
    }

    const float* pbr = pb + ((size_t)h * 256 + s) * 7;
    float mx = -1e30f;
#pragma unroll
    for (int w = 0; w < 7; ++w) {
        sc[w] = sc[w] * 0.125f + pbr[w];
        mx = fmaxf(mx, sc[w]);
    }
    float p[7], sum = 0.f;
#pragma unroll
    for (int w = 0; w < 7; ++w) {
        p[w] = __expf(sc[w] - mx);
        sum += p[w];
    }
    const float inv = 1.f / sum;
#pragma unroll
    for (int w = 0; w < 7; ++w) p[w] *= inv;

    // ---- output: accumulate all 64 elems in regs, then one contiguous 128-B store ----
    uint4 ov[8];
#pragma unroll
    for (int c = 0; c < 8; ++c) {
        float o[8] = {0.f, 0.f, 0.f, 0.f, 0.f, 0.f, 0.f, 0.f};
#pragma unroll
        for (int w = 0; w < 7; ++w) {
            int sp = s + w - 3;
            if ((unsigned)sp < 256u) {
                uint4 vc = smem[2048 + sp * 8 + (c ^ (sp & 7))];
                float vf[8];
                unpack8(vc, vf);
#pragma unroll
                for (int j = 0; j < 8; ++j) o[j] += p[w] * vf[j];
            }
        }
        ov[c].x = pack2(o[0], o[1]);
        ov[c].y = pack2(o[2], o[3]);
        ov[c].z = pack2(o[4], o[5]);
        ov[c].w = pack2(o[6], o[7]);
    }

    uint16_t* orow = attn + ((size_t)(bn * 256 + s)) * 512 + h * 64;
#pragma unroll
    for (int c = 0; c < 8; ++c) *(uint4*)(orow + c * 8) = ov[c];
}

// ---------------------------------------------------------------------------
extern "C" void kernel_launch(void* const* d_in, const int* in_sizes, int n_in,
                              void* d_out, int out_size, void* d_ws, size_t ws_size,
                              hipStream_t stream) {
    const float* X    = (const float*)d_in[0];  // 32768 x 512 fp32
    const float* pb   = (const float*)d_in[1];  // 8 x 256 x 7 fp32
    const float* Wqkv = (const float*)d_in[2];  // 512 x 1536 fp32
    const float* Wout = (const float*)d_in[3];  // 512 x 512 fp32
    float* out = (float*)d_out;                 // 32768 x 512 fp32

    char* ws = (char*)d_ws;
    uint16_t* WqkvT = (uint16_t*)(ws);                  // 1536x512 bf16 = 1.5 MB
    uint16_t* WoutT = (uint16_t*)(ws + 1572864);        // 512x512  bf16 = 0.5 MB
    uint16_t* qkvb  = (uint16_t*)(ws + 2097152);        // 32768x1536 bf16 = 96 MB
    uint16_t* Xb    = (uint16_t*)(ws + 102760448);      // 32768x512 bf16 = 32 MB
    uint16_t* attnb = Xb;  // alias: Xb dead after GEMM1 (stream-ordered)

    cvt_f32_bf16<<<(32768 * 512 / 8 + 255) / 256, 256, 0, stream>>>(X, Xb, 32768 * 512 / 8);
    transpose_cvt<<<(512 * 1536 + 255) / 256, 256, 0, stream>>>(Wqkv, WqkvT, 512, 1536);
    transpose_cvt<<<(512 * 512 + 255) / 256, 256, 0, stream>>>(Wout, WoutT, 512, 512);

    gemm256<false><<<dim3(128, 6), 512, 0, stream>>>(Xb, WqkvT, qkvb, 32768, 1536, 512);
    local_attn<<<1024, 256, 0, stream>>>(qkvb, pb, attnb);
    gemm256<true><<<dim3(128, 2), 512, 0, stream>>>(attnb, WoutT, out, 32768, 512, 512);
}

// Round 3
// 251.764 us; speedup vs baseline: 1.0596x; 1.0255x over previous
//
#include <hip/hip_runtime.h>
#include <hip/hip_bf16.h>
#include <cstdint>

// B=2, HW=64 -> 128 rows of S=256; M = 32768. D=512, HEADS=8, DK=64,
// 3*H*DK=1536, KSIZE=7. Inputs/outputs fp32; internal compute bf16 MFMA.

typedef __bf16 bf16x8 __attribute__((ext_vector_type(8)));
typedef float f32x4 __attribute__((ext_vector_type(4)));

__device__ __forceinline__ uint16_t f2bf(float f) {
    uint32_t u = __builtin_bit_cast(uint32_t, f);
    return (uint16_t)((u + 0x7fffu + ((u >> 16) & 1u)) >> 16);
}
__device__ __forceinline__ float bflo(uint32_t u) { return __builtin_bit_cast(float, u << 16); }
__device__ __forceinline__ float bfhi(uint32_t u) { return __builtin_bit_cast(float, u & 0xffff0000u); }

__device__ __forceinline__ void unpack8(uint4 v, float* f) {
    f[0] = bflo(v.x); f[1] = bfhi(v.x);
    f[2] = bflo(v.y); f[3] = bfhi(v.y);
    f[4] = bflo(v.z); f[5] = bfhi(v.z);
    f[6] = bflo(v.w); f[7] = bfhi(v.w);
}
__device__ __forceinline__ uint32_t pack2(float a, float b) {
    return (uint32_t)f2bf(a) | ((uint32_t)f2bf(b) << 16);
}

#define GLOAD_LDS16(gp, lp)                                                        \
    __builtin_amdgcn_global_load_lds((const __attribute__((address_space(1))) void*)(gp), \
                                     (__attribute__((address_space(3))) void*)(lp), 16, 0, 0)

// Inline-asm LDS read: invisible to the compiler's waitcnt/alias tracking.
// Volatile asm keeps mutual program order with the waitcnt/barrier asm, so the
// issue/wait counting below is exact. Caller owns lgkmcnt discipline.
__device__ __forceinline__ bf16x8 ds_read16(const uint16_t* p) {
    bf16x8 r;
    asm volatile("ds_read_b128 %0, %1"
                 : "=v"(r)
                 : "v"((const __attribute__((address_space(3))) void*)p));
    return r;
}

// ---------------------------------------------------------------------------
// fp32 -> bf16 bulk convert, 8 elems/thread
// ---------------------------------------------------------------------------
__global__ void cvt_f32_bf16(const float* __restrict__ in, uint16_t* __restrict__ out, int n8) {
    int i = blockIdx.x * 256 + threadIdx.x;
    if (i >= n8) return;
    const float4* p = (const float4*)in + (size_t)i * 2;
    float4 a = p[0], b = p[1];
    uint4 o;
    o.x = pack2(a.x, a.y);
    o.y = pack2(a.z, a.w);
    o.z = pack2(b.x, b.y);
    o.w = pack2(b.z, b.w);
    *((uint4*)out + i) = o;
}

// ---------------------------------------------------------------------------
// transpose + convert: out[c*R + r] = bf16(in[r*C + c])
// ---------------------------------------------------------------------------
__global__ void transpose_cvt(const float* __restrict__ in, uint16_t* __restrict__ out,
                              int R, int C) {
    int idx = blockIdx.x * 256 + threadIdx.x;
    if (idx >= R * C) return;
    int r = idx / C;
    int c = idx - r * C;
    out[(size_t)c * R + r] = f2bf(in[idx]);
}

// ---------------------------------------------------------------------------
// 256x256-tile bf16 GEMM, derived-wait pipeline (one barrier per K-tile).
// C[M,N] = A[M,K] @ B[K,N], B given transposed (BT[N,K]).
// 512 threads = 8 waves (2 M-waves x 4 N-waves), per-wave 128x64 output
// (acc[8][4] of 16x16x32 frags). BK=64, A and B double-buffered, LDS 128 KiB.
//
// LDS swizzle: 16B k-chunk index cc stored at cc ^ (row&7); global source is
// pre-swizzled so global_load_lds dest stays linear; ds_read applies the same
// XOR (both-sides rule). Bank-conflict-free (verified: counter = 0).
//
// Per K-tile t (buf b = t&1), NO per-phase barriers -- waves free-run inside
// the tile so ds_reads of one wave overlap MFMA of others, and each wave's
// own reads are issued one MFMA-cluster ahead and waited with counted
// lgkmcnt(4):
//   issue bfr(8 B-frags) + a0(A0,A1)   [12 ds]
//   stage A-h0,B-h0 (t+1 -> buf b^1)
//   issue a1(A2,A3)                    [16 ds]
//   stage A-h1,B-h1 (t+1 -> buf b^1)
//   lgkmcnt(4)  -> 12 oldest done -> MFMA cluster 0 (a0)   [a1 in flight]
//   issue a0(A4,A5); lgkmcnt(4) -> MFMA cluster 1 (a1)
//   issue a1(A6,A7); lgkmcnt(4) -> MFMA cluster 2 (a0)
//   lgkmcnt(0)                  -> MFMA cluster 3 (a1)
//   vmcnt(0) [own 8 staging loads, issued ~2500 cyc earlier] ; s_barrier
// Race-safety: all reads target buf b only, all stages target buf b^1 only;
// the tile-end (vmcnt(0); barrier) pair guarantees every wave's DMA landed
// and every wave finished reading b before b is overwritten in tile t+2.
// DS-queue FIFO makes lgkmcnt(4) == "oldest (n-4) reads complete".
// Assumes K % 64 == 0, K/64 >= 2 (here K=512 -> NT=8).
// ---------------------------------------------------------------------------
template <bool F32OUT>
__global__ __launch_bounds__(512, 2)
void gemm256(const uint16_t* __restrict__ A, const uint16_t* __restrict__ BT,
             void* __restrict__ Cout, int M, int N, int K) {
    __shared__ __align__(16) uint16_t lds[65536];  // [0,32768): A bufs, [32768,65536): B bufs

    const int tid  = threadIdx.x;
    const int lane = tid & 63;
    const int wv   = tid >> 6;
    const int r    = lane & 15;
    const int quad = lane >> 4;
    const int wr   = wv >> 2;   // 0..1  (M wave)
    const int wc   = wv & 3;    // 0..3  (N wave)
    const long bm0 = (long)blockIdx.x * 256;
    const long bn0 = (long)blockIdx.y * 256;
    const int NT   = K >> 6;

    // ---- staging constants: thread handles 16B chunks c0, c1 of each half ----
    const int c0 = tid, c1 = tid + 512;
    const int row0 = c0 >> 3, row1 = c1 >> 3;          // row within 128-row half
    const int sw0 = ((c0 & 7) ^ (row0 & 7)) * 8;       // pre-swizzled k-chunk (elems)
    const int sw1 = ((c1 & 7) ^ (row1 & 7)) * 8;
    const uint16_t* pA0 = A  + (bm0 + row0) * (long)K + sw0;
    const uint16_t* pA1 = A  + (bm0 + row1) * (long)K + sw1;
    const uint16_t* pB0 = BT + (bn0 + row0) * (long)K + sw0;
    const uint16_t* pB1 = BT + (bn0 + row1) * (long)K + sw1;
    const long hstep = 128 * (long)K;

#define STAGE_A(b_, h_, t_) do {                                                        \
        GLOAD_LDS16(pA0 + (h_) * hstep + (t_) * 64,                                     \
                    &lds[(b_) * 16384 + (h_) * 8192 + c0 * 8]);                         \
        GLOAD_LDS16(pA1 + (h_) * hstep + (t_) * 64,                                     \
                    &lds[(b_) * 16384 + (h_) * 8192 + c1 * 8]);                         \
    } while (0)
#define STAGE_B(b_, h_, t_) do {                                                        \
        GLOAD_LDS16(pB0 + (h_) * hstep + (t_) * 64,                                     \
                    &lds[32768 + (b_) * 16384 + (h_) * 8192 + c0 * 8]);                 \
        GLOAD_LDS16(pB1 + (h_) * hstep + (t_) * 64,                                     \
                    &lds[32768 + (b_) * 16384 + (h_) * 8192 + c1 * 8]);                 \
    } while (0)

    // ---- compute-side constants ----
    const int swk0 = ((0 + quad) ^ (r & 7)) * 8;   // kk=0 swizzled chunk (elems)
    const int swk1 = ((4 + quad) ^ (r & 7)) * 8;   // kk=1
    const int arow = (wr * 128 + r) * 64;          // elem offset of A row base
    const int brow = (wc * 64 + r) * 64;           // elem offset of B row base

#define DS_A(mf_, kk_) ds_read16(&lds[aoff + arow + (mf_) * 1024 + ((kk_) ? swk1 : swk0)])
#define DS_B(nf_, kk_) ds_read16(&lds[boff + brow + (nf_) * 1024 + ((kk_) ? swk1 : swk0)])

// counted wait + fence (rule #18: stop MFMA hoisting above the wait)
#define WAITK4 do { asm volatile("s_waitcnt lgkmcnt(4)" ::: "memory");                  \
                    __builtin_amdgcn_sched_barrier(0); } while (0)
#define WAITK0 do { asm volatile("s_waitcnt lgkmcnt(0)" ::: "memory");                  \
                    __builtin_amdgcn_sched_barrier(0); } while (0)

#define MFMA_CL(mbase_, ar_)                                                            \
    __builtin_amdgcn_s_setprio(1);                                                      \
    _Pragma("unroll")                                                                   \
    for (int kk = 0; kk < 2; ++kk)                                                      \
        _Pragma("unroll")                                                               \
        for (int mi = 0; mi < 2; ++mi)                                                  \
            _Pragma("unroll")                                                           \
            for (int nf = 0; nf < 4; ++nf)                                              \
                acc[(mbase_) + mi][nf] = __builtin_amdgcn_mfma_f32_16x16x32_bf16(       \
                    ar_[mi][kk], bfr[nf][kk], acc[(mbase_) + mi][nf], 0, 0, 0);         \
    __builtin_amdgcn_s_setprio(0);

    f32x4 acc[8][4];
#pragma unroll
    for (int mf = 0; mf < 8; ++mf)
#pragma unroll
        for (int nf = 0; nf < 4; ++nf) acc[mf][nf] = (f32x4){0.f, 0.f, 0.f, 0.f};

    // ---- prologue: stage tile0 into buf0, wait, barrier ----
    STAGE_A(0, 0, 0); STAGE_A(0, 1, 0);
    STAGE_B(0, 0, 0); STAGE_B(0, 1, 0);
    asm volatile("s_waitcnt vmcnt(0)" ::: "memory");
    __builtin_amdgcn_s_barrier();

    for (int t = 0; t < NT; ++t) {
        const int b    = t & 1;
        const int aoff = b * 16384;
        const int boff = 32768 + b * 16384;
        const bool pf  = (t + 1 < NT);

        bf16x8 bfr[4][2];
        bf16x8 a0[2][2], a1[2][2];

        // ---- issue cluster-0 reads (12) + first half of staging ----
#pragma unroll
        for (int nf = 0; nf < 4; ++nf) { bfr[nf][0] = DS_B(nf, 0); bfr[nf][1] = DS_B(nf, 1); }
        a0[0][0] = DS_A(0, 0); a0[0][1] = DS_A(0, 1);
        a0[1][0] = DS_A(1, 0); a0[1][1] = DS_A(1, 1);
        if (pf) { STAGE_A(b ^ 1, 0, t + 1); STAGE_B(b ^ 1, 0, t + 1); }

        // ---- issue cluster-1 reads (4) + second half of staging ----
        a1[0][0] = DS_A(2, 0); a1[0][1] = DS_A(2, 1);
        a1[1][0] = DS_A(3, 0); a1[1][1] = DS_A(3, 1);
        if (pf) { STAGE_A(b ^ 1, 1, t + 1); STAGE_B(b ^ 1, 1, t + 1); }

        WAITK4;                 // 12 oldest (bfr + a0) done, a1 in flight
        MFMA_CL(0, a0)

        a0[0][0] = DS_A(4, 0); a0[0][1] = DS_A(4, 1);
        a0[1][0] = DS_A(5, 0); a0[1][1] = DS_A(5, 1);
        WAITK4;                 // a1 done, a0(45) in flight
        MFMA_CL(2, a1)

        a1[0][0] = DS_A(6, 0); a1[0][1] = DS_A(6, 1);
        a1[1][0] = DS_A(7, 0); a1[1][1] = DS_A(7, 1);
        WAITK4;                 // a0(45) done, a1(67) in flight
        MFMA_CL(4, a0)

        WAITK0;                 // a1(67) done
        MFMA_CL(6, a1)

        if (pf) {
            // own staging loads issued ~one full tile ago -> effectively counted
            asm volatile("s_waitcnt vmcnt(0)" ::: "memory");
            __builtin_amdgcn_s_barrier();
        }
    }

    // ---- epilogue: D[row = quad*4 + i][col = r] per 16x16 frag ----
#pragma unroll
    for (int mf = 0; mf < 8; ++mf) {
#pragma unroll
        for (int i = 0; i < 4; ++i) {
            long m = bm0 + wr * 128 + mf * 16 + quad * 4 + i;
            if (F32OUT) {
                float* crow = (float*)Cout + m * (long)N + bn0 + wc * 64 + r;
#pragma unroll
                for (int nf = 0; nf < 4; ++nf) crow[nf * 16] = acc[mf][nf][i];
            } else {
                uint16_t* crow = (uint16_t*)Cout + m * (long)N + bn0 + wc * 64 + r;
#pragma unroll
                for (int nf = 0; nf < 4; ++nf) crow[nf * 16] = f2bf(acc[mf][nf][i]);
            }
        }
    }
#undef STAGE_A
#undef STAGE_B
#undef DS_A
#undef DS_B
#undef WAITK4
#undef WAITK0
#undef MFMA_CL
}

// ---------------------------------------------------------------------------
// Local window attention, LDS-staged K/V.
// Block = (bn, head), 256 threads, thread = s.
// LDS: K tile + V tile = 2 * 256 rows * 64 elems * 2B = 64 KB (2 blocks/CU).
// 16-B chunk column is XOR-swizzled by (sp&7) -> conflict-free for the
// stride-128B compute-phase reads without padding bytes.
// Q is per-thread (read once from global, full cache-line use) in registers.
// Padded window entries (sp out of range): score = bias only, v contributes 0.
// ---------------------------------------------------------------------------
__global__ __launch_bounds__(256, 2)
void local_attn(const uint16_t* __restrict__ qkv, const float* __restrict__ pb,
                uint16_t* __restrict__ attn) {
    __shared__ uint4 smem[4096];  // [0,2048): K chunks, [2048,4096): V chunks

    const int h  = blockIdx.x & 7;
    const int bn = blockIdx.x >> 3;
    const int s  = threadIdx.x;
    const size_t base = (size_t)bn * 256 * 1536;

    // ---- stage K,V: 4096 16-B chunks, 16 per thread, coalesced ----
#pragma unroll
    for (int it = 0; it < 16; ++it) {
        int i   = threadIdx.x + it * 256;
        int a   = i >> 11;        // 0=K, 1=V
        int idx = i & 2047;
        int sp  = idx >> 3;
        int c8  = idx & 7;
        const uint16_t* src = qkv + base + (size_t)sp * 1536 + 512 + a * 512 + h * 64 + c8 * 8;
        smem[a * 2048 + sp * 8 + (c8 ^ (sp & 7))] = *(const uint4*)src;
    }

    // ---- load own Q row into registers (8 x 16B = 128 B) ----
    const uint16_t* qrow = qkv + base + (size_t)s * 1536 + h * 64;
    uint4 qc[8];
#pragma unroll
    for (int c = 0; c < 8; ++c) qc[c] = *(const uint4*)(qrow + c * 8);

    __syncthreads();

    // ---- scores ----
    float sc[7];
#pragma unroll
    for (int w = 0; w < 7; ++w) sc[w] = 0.f;

#pragma unroll
    for (int c = 0; c < 8; ++c) {
        float qf[8];
        unpack8(qc[c], qf);
#pragma unroll
        for (int w = 0; w < 7; ++w) {
            int sp = s + w - 3;
            if ((unsigned)sp < 256u) {
                uint4 kc = smem[sp * 8 + (c ^ (sp & 7))];
                float kf[8];
                unpack8(kc, kf);
#pragma unroll
                for (int j = 0; j < 8; ++j) sc[w] += qf[j] * kf[j];
            }
        }
    }

    const float* pbr = pb + ((size_t)h * 256 + s) * 7;
    float mx = -1e30f;
#pragma unroll
    for (int w = 0; w < 7; ++w) {
        sc[w] = sc[w] * 0.125f + pbr[w];
        mx = fmaxf(mx, sc[w]);
    }
    float p[7], sum = 0.f;
#pragma unroll
    for (int w = 0; w < 7; ++w) {
        p[w] = __expf(sc[w] - mx);
        sum += p[w];
    }
    const float inv = 1.f / sum;
#pragma unroll
    for (int w = 0; w < 7; ++w) p[w] *= inv;

    // ---- output: accumulate all 64 elems in regs, then one contiguous 128-B store ----
    uint4 ov[8];
#pragma unroll
    for (int c = 0; c < 8; ++c) {
        float o[8] = {0.f, 0.f, 0.f, 0.f, 0.f, 0.f, 0.f, 0.f};
#pragma unroll
        for (int w = 0; w < 7; ++w) {
            int sp = s + w - 3;
            if ((unsigned)sp < 256u) {
                uint4 vc = smem[2048 + sp * 8 + (c ^ (sp & 7))];
                float vf[8];
                unpack8(vc, vf);
#pragma unroll
                for (int j = 0; j < 8; ++j) o[j] += p[w] * vf[j];
            }
        }
        ov[c].x = pack2(o[0], o[1]);
        ov[c].y = pack2(o[2], o[3]);
        ov[c].z = pack2(o[4], o[5]);
        ov[c].w = pack2(o[6], o[7]);
    }

    uint16_t* orow = attn + ((size_t)(bn * 256 + s)) * 512 + h * 64;
#pragma unroll
    for (int c = 0; c < 8; ++c) *(uint4*)(orow + c * 8) = ov[c];
}

// ---------------------------------------------------------------------------
extern "C" void kernel_launch(void* const* d_in, const int* in_sizes, int n_in,
                              void* d_out, int out_size, void* d_ws, size_t ws_size,
                              hipStream_t stream) {
    const float* X    = (const float*)d_in[0];  // 32768 x 512 fp32
    const float* pb   = (const float*)d_in[1];  // 8 x 256 x 7 fp32
    const float* Wqkv = (const float*)d_in[2];  // 512 x 1536 fp32
    const float* Wout = (const float*)d_in[3];  // 512 x 512 fp32
    float* out = (float*)d_out;                 // 32768 x 512 fp32

    char* ws = (char*)d_ws;
    uint16_t* WqkvT = (uint16_t*)(ws);                  // 1536x512 bf16 = 1.5 MB
    uint16_t* WoutT = (uint16_t*)(ws + 1572864);        // 512x512  bf16 = 0.5 MB
    uint16_t* qkvb  = (uint16_t*)(ws + 2097152);        // 32768x1536 bf16 = 96 MB
    uint16_t* Xb    = (uint16_t*)(ws + 102760448);      // 32768x512 bf16 = 32 MB
    uint16_t* attnb = Xb;  // alias: Xb dead after GEMM1 (stream-ordered)

    cvt_f32_bf16<<<(32768 * 512 / 8 + 255) / 256, 256, 0, stream>>>(X, Xb, 32768 * 512 / 8);
    transpose_cvt<<<(512 * 1536 + 255) / 256, 256, 0, stream>>>(Wqkv, WqkvT, 512, 1536);
    transpose_cvt<<<(512 * 512 + 255) / 256, 256, 0, stream>>>(Wout, WoutT, 512, 512);

    gemm256<false><<<dim3(128, 6), 512, 0, stream>>>(Xb, WqkvT, qkvb, 32768, 1536, 512);
    local_attn<<<1024, 256, 0, stream>>>(qkvb, pb, attnb);
    gemm256<true><<<dim3(128, 2), 512, 0, stream>>>(attnb, WoutT, out, 32768, 512, 512);
}